// Round 3
// baseline (113.686 us; speedup 1.0000x reference)
//
#include <hip/hip_runtime.h>

// Problem constants (match reference)
#define C_DIM 16
#define R_DIM 1024
#define T_DIM 4096
#define ROWS_PER_BLOCK 16   // rr rows written per block

// ws layout: [0, C*T*4) = 256 KB int32 maxrho[C][T].
// out: float out[C][R][T] = 256 MB.

__global__ void scatter_max(const int* __restrict__ rho,
                            const int* __restrict__ theta,
                            const int* __restrict__ f,
                            int* __restrict__ maxrho, int n) {
    int i = blockIdx.x * blockDim.x + threadIdx.x;
    if (i < n) {
        atomicMax(&maxrho[f[i] * T_DIM + theta[i]], rho[i]);
    }
}

// One block per (c, 16-row chunk). 256 threads.
// Prologue: load + resolve the 4096-float val row into VGPRs (16 floats/thread).
// Hot loop: for each of 16 rows, pure subtract + float4 stores (no loads).
__global__ __launch_bounds__(256) void write_out(const int* __restrict__ maxrho,
                                                 const float* __restrict__ rp,
                                                 const float* __restrict__ r,
                                                 float* __restrict__ out) {
    const int c     = blockIdx.x >> 6;                    // / (R/ROWS_PER_BLOCK)
    const int chunk = blockIdx.x & 63;
    const int rr0   = chunk * ROWS_PER_BLOCK;

    // Load maxrho row (int) and resolve via rp (4 KB, L1-resident) once.
    const int4* mrow = reinterpret_cast<const int4*>(maxrho + c * T_DIM);
    float v[16];
#pragma unroll
    for (int k = 0; k < 4; ++k) {
        int4 m = mrow[threadIdx.x + k * 256];
        v[4 * k + 0] = rp[m.x < 0 ? R_DIM : m.x];
        v[4 * k + 1] = rp[m.y < 0 ? R_DIM : m.y];
        v[4 * k + 2] = rp[m.z < 0 ? R_DIM : m.z];
        v[4 * k + 3] = rp[m.w < 0 ? R_DIM : m.w];
    }

    float* obase = out + ((size_t)c * R_DIM + rr0) * T_DIM;

    for (int j = 0; j < ROWS_PER_BLOCK; ++j) {
        float rv = r[rr0 + j];                            // wave-uniform scalar load
        float4* orow = reinterpret_cast<float4*>(obase + (size_t)j * T_DIM);
#pragma unroll
        for (int k = 0; k < 4; ++k) {
            float4 o = { v[4 * k + 0] - rv, v[4 * k + 1] - rv,
                         v[4 * k + 2] - rv, v[4 * k + 3] - rv };
            orow[threadIdx.x + k * 256] = o;
        }
    }
}

extern "C" void kernel_launch(void* const* d_in, const int* in_sizes, int n_in,
                              void* d_out, int out_size, void* d_ws, size_t ws_size,
                              hipStream_t stream) {
    const int*   rho   = (const int*)d_in[0];
    const int*   theta = (const int*)d_in[1];
    const int*   f     = (const int*)d_in[2];
    const float* rp    = (const float*)d_in[3];
    const float* r     = (const float*)d_in[4];
    float* out = (float*)d_out;

    int* maxrho = (int*)d_ws;               // 256 KB
    const int n = in_sizes[0];

    // 1. maxrho = -1 (0xFF bytes), re-done every call
    hipMemsetAsync(maxrho, 0xFF, (size_t)C_DIM * T_DIM * sizeof(int), stream);

    // 2. scatter atomicMax
    scatter_max<<<(n + 255) / 256, 256, 0, stream>>>(rho, theta, f, maxrho, n);

    // 3. fused resolve + outer-product stream: 16*64 = 1024 blocks
    write_out<<<C_DIM * (R_DIM / ROWS_PER_BLOCK), 256, 0, stream>>>(maxrho, rp, r, out);
}

// Round 4
// 73.164 us; speedup vs baseline: 1.5538x; 1.5538x over previous
//
#include <hip/hip_runtime.h>

// Problem constants (match reference)
#define C_DIM 16
#define R_DIM 1024
#define T_DIM 4096
#define ROWS_PER_BLOCK 16   // rr rows written per block

// ws layout: [0, C*T*4) = 256 KB, first int32 maxrho[C][T],
// then resolved IN-PLACE to float val[C][T] = rp[m < 0 ? R : m].
// out: float out[C][R][T] = 256 MB.

__global__ void scatter_max(const int* __restrict__ rho,
                            const int* __restrict__ theta,
                            const int* __restrict__ f,
                            int* __restrict__ maxrho, int n) {
    int i = blockIdx.x * blockDim.x + threadIdx.x;
    if (i < n) {
        atomicMax(&maxrho[f[i] * T_DIM + theta[i]], rho[i]);
    }
}

// maxrho (int) -> val (float), in place. 65536 gathers TOTAL (done once,
// not per output block — R3's mistake was 4M redundant gathers).
__global__ void resolve(int* __restrict__ slot,
                        const float* __restrict__ rp) {
    int i = blockIdx.x * blockDim.x + threadIdx.x;   // < C*T
    int m = slot[i];
    float v = rp[m < 0 ? R_DIM : m];
    reinterpret_cast<float*>(slot)[i] = v;
}

// One block per (c, 16-row chunk). 256 threads.
// Prologue: 16 contiguous float4 loads -> val row in VGPRs (no gathers).
// Hot loop: 16 rows x 4 float4 stores per thread, zero vector loads.
__global__ __launch_bounds__(256) void write_out(const float* __restrict__ val,
                                                 const float* __restrict__ r,
                                                 float* __restrict__ out) {
    const int c     = blockIdx.x >> 6;                    // / (R/ROWS_PER_BLOCK)
    const int chunk = blockIdx.x & 63;
    const int rr0   = chunk * ROWS_PER_BLOCK;

    const float4* vrow = reinterpret_cast<const float4*>(val + c * T_DIM);
    float4 v[4];
#pragma unroll
    for (int k = 0; k < 4; ++k) v[k] = vrow[threadIdx.x + k * 256];

    float* obase = out + ((size_t)c * R_DIM + rr0) * T_DIM;

    for (int j = 0; j < ROWS_PER_BLOCK; ++j) {
        float rv = r[rr0 + j];                            // wave-uniform scalar load
        float4* orow = reinterpret_cast<float4*>(obase + (size_t)j * T_DIM);
#pragma unroll
        for (int k = 0; k < 4; ++k) {
            float4 o = { v[k].x - rv, v[k].y - rv, v[k].z - rv, v[k].w - rv };
            orow[threadIdx.x + k * 256] = o;
        }
    }
}

extern "C" void kernel_launch(void* const* d_in, const int* in_sizes, int n_in,
                              void* d_out, int out_size, void* d_ws, size_t ws_size,
                              hipStream_t stream) {
    const int*   rho   = (const int*)d_in[0];
    const int*   theta = (const int*)d_in[1];
    const int*   f     = (const int*)d_in[2];
    const float* rp    = (const float*)d_in[3];
    const float* r     = (const float*)d_in[4];
    float* out = (float*)d_out;

    int* slot = (int*)d_ws;                 // 256 KB
    const int n = in_sizes[0];

    // 1. maxrho = -1 (0xFF bytes), re-done every call
    hipMemsetAsync(slot, 0xFF, (size_t)C_DIM * T_DIM * sizeof(int), stream);

    // 2. scatter atomicMax
    scatter_max<<<(n + 255) / 256, 256, 0, stream>>>(rho, theta, f, slot, n);

    // 3. resolve maxrho -> rp value, ONCE (65536 elems)
    resolve<<<(C_DIM * T_DIM) / 256, 256, 0, stream>>>(slot, rp);

    // 4. outer-product stream: 1024 blocks, pure store hot loop
    write_out<<<C_DIM * (R_DIM / ROWS_PER_BLOCK), 256, 0, stream>>>(
        (const float*)slot, r, out);
}